// Round 5
// baseline (302.021 us; speedup 1.0000x reference)
//
#include <hip/hip_runtime.h>
#include <hip/hip_bf16.h>

typedef __bf16 bf16_t;
typedef __bf16 bf16x8 __attribute__((ext_vector_type(8)));
typedef __bf16 bf16x4 __attribute__((ext_vector_type(4)));
typedef float f32x4 __attribute__((ext_vector_type(4)));

#define NB 8
#define NS 4096
#define NH 256
#define NF 512
#define NE 16
#define NTOK (NB*NS)          // 32768
#define TT 64                 // tokens per tile
#define EW (NF*NH)            // 131072 elements per expert weight

// ---------------------------------------------------------------------------
// Kernel 1: transpose+convert weights (fp32 in, bf16 out), layouts built for
// the moe kernel's exact access patterns:
//  w1t: per expert, 8 chunk-images of 32KB; chunk c holds f in [c*64,c*64+64)
//       element (f,k) at c*16384 + fl*256 + gs*8 + (k&7),
//       fl=f&63, g=k>>3, gs=(g&24)|((g^fl)&7)   [XOR bank swizzle]
//  w2t: granule-major: element (h,f) at (f>>3)*2048 + h*8 + (f&7)
//       -> a wave B-frag read = 4 contiguous 256B runs
// ---------------------------------------------------------------------------
__global__ __launch_bounds__(256) void transpose_kernel(
    const float* __restrict__ w1, const float* __restrict__ w2,
    bf16_t* __restrict__ w1t, bf16_t* __restrict__ w2t)
{
    __shared__ float tile[32][33];
    int bid = blockIdx.x;
    const float* src; bf16_t* dst; int R, C; int isw1;
    if (bid < 2048) { src = w1; dst = w1t; R = NH; C = NF; isw1 = 1; }
    else            { bid -= 2048; src = w2; dst = w2t; R = NF; C = NH; isw1 = 0; }
    const int tilesPerE = 128;
    int e = bid / tilesPerE;
    int t = bid % tilesPerE;
    int tcols = C / 32;
    int tr = (t / tcols) * 32, tc = (t % tcols) * 32;
    src += (size_t)e * R * C;
    dst += (size_t)e * EW;
    int tx = threadIdx.x & 31, ty0 = threadIdx.x >> 5;
    #pragma unroll
    for (int i = 0; i < 4; i++) {
        int ty = ty0 + i * 8;
        tile[ty][tx] = src[(size_t)(tr + ty) * C + tc + tx];
    }
    __syncthreads();
    #pragma unroll
    for (int i = 0; i < 4; i++) {
        int ty = ty0 + i * 8;
        int drow = tc + ty;          // f for w1, h for w2
        int dcol = tr + tx;          // k for w1, f for w2
        size_t idx;
        if (isw1) {
            int c = drow >> 6, fl = drow & 63;
            int g = dcol >> 3;
            int gs = (g & 24) | ((g ^ fl) & 7);
            idx = c * 16384 + fl * 256 + gs * 8 + (dcol & 7);
        } else {
            idx = (size_t)(dcol >> 3) * 2048 + drow * 8 + (dcol & 7);
        }
        dst[idx] = (bf16_t)tile[tx][ty];
    }
}

// ---------------------------------------------------------------------------
// Kernel 2a: gate — logits, top-2, softmax(2); per-block LDS histogram gives
// each pick a deterministic-enough (e,block,rank) key; NO global atomics.
// Also converts x -> bf16 (fused).
// ---------------------------------------------------------------------------
__global__ __launch_bounds__(256) void gate_kernel(
    const float* __restrict__ x, const float* __restrict__ gate_w,
    const float* __restrict__ gate_b,
    int* __restrict__ blockcnt,      // [E][128]
    int* __restrict__ pick_e, int* __restrict__ pick_r,
    float2* __restrict__ pick_w, bf16_t* __restrict__ xb)
{
    __shared__ float gws[NH * NE];   // 16 KB, [h*16+e]
    __shared__ int lcnt[NE];

    for (int i = threadIdx.x; i < NH * NE; i += 256) gws[i] = gate_w[i];
    if (threadIdx.x < NE) lcnt[threadIdx.x] = 0;
    __syncthreads();

    int tok = blockIdx.x * 256 + threadIdx.x;
    const float4* xr = (const float4*)(x + (size_t)tok * NH);
    bf16x4* xbr = (bf16x4*)(xb + (size_t)tok * NH);
    float acc[NE];
    #pragma unroll
    for (int e = 0; e < NE; e++) acc[e] = gate_b[e];
    #pragma unroll 4
    for (int h4 = 0; h4 < NH / 4; h4++) {
        float4 xv = xr[h4];
        bf16x4 xo;
        xo[0] = (bf16_t)xv.x; xo[1] = (bf16_t)xv.y;
        xo[2] = (bf16_t)xv.z; xo[3] = (bf16_t)xv.w;
        xbr[h4] = xo;
        #pragma unroll
        for (int j = 0; j < 4; j++) {
            float xs = (j == 0) ? xv.x : (j == 1) ? xv.y : (j == 2) ? xv.z : xv.w;
            const float* g = &gws[(h4 * 4 + j) * NE];
            #pragma unroll
            for (int e = 0; e < NE; e++) acc[e] += xs * g[e];
        }
    }
    // top-2 (jax.lax.top_k order: strict >, earlier index wins ties)
    float v0 = -1e30f, v1 = -1e30f; int i0 = 0, i1 = 0;
    #pragma unroll
    for (int e = 0; e < NE; e++) {
        float a = acc[e];
        if (a > v0)      { v1 = v0; i1 = i0; v0 = a; i0 = e; }
        else if (a > v1) { v1 = a; i1 = e; }
    }
    float e1 = __expf(v1 - v0);
    float s  = 1.f + e1;
    int r0 = atomicAdd(&lcnt[i0], 1);
    int r1 = atomicAdd(&lcnt[i1], 1);
    pick_e[tok] = i0 | (i1 << 8);
    pick_r[tok] = r0 | (r1 << 16);
    pick_w[tok] = make_float2(1.f / s, e1 / s);
    __syncthreads();
    if (threadIdx.x < NE)
        blockcnt[threadIdx.x * 128 + blockIdx.x] = lcnt[threadIdx.x];
}

// ---------------------------------------------------------------------------
// Kernel 2b: scan — per-expert exclusive prefix over 128 block counts
// ---------------------------------------------------------------------------
__global__ __launch_bounds__(256) void scan_kernel(
    const int* __restrict__ blockcnt, int* __restrict__ segb,
    int* __restrict__ counts)
{
    __shared__ int cnts[NE * 128];
    for (int i = threadIdx.x; i < NE * 128; i += 256) cnts[i] = blockcnt[i];
    __syncthreads();
    if (threadIdx.x < NE) {
        int e = threadIdx.x, run = 0;
        for (int b = 0; b < 128; b++) {
            segb[e * 128 + b] = run;
            run += cnts[e * 128 + b];
        }
        counts[e] = run;
    }
}

// ---------------------------------------------------------------------------
// Kernel 2c: scatter picks to contiguous per-expert buckets (no atomics)
// ---------------------------------------------------------------------------
__global__ __launch_bounds__(256) void scatter_kernel(
    const int* __restrict__ pick_e, const int* __restrict__ pick_r,
    const float2* __restrict__ pick_w, const int* __restrict__ segb,
    int* __restrict__ bucket_enc, float* __restrict__ bucket_gw)
{
    int tok = blockIdx.x * 256 + threadIdx.x;
    int blk = tok >> 8;
    int pe = pick_e[tok], pr = pick_r[tok];
    float2 w = pick_w[tok];
    int e0 = pe & 255, e1 = (pe >> 8) & 255;
    int p0 = segb[e0 * 128 + blk] + (pr & 0xFFFF);
    int p1 = segb[e1 * 128 + blk] + (pr >> 16);
    bucket_enc[e0 * NTOK + p0] = tok;
    bucket_gw [e0 * NTOK + p0] = w.x;
    bucket_enc[e1 * NTOK + p1] = tok | (1 << 20);
    bucket_gw [e1 * NTOK + p1] = w.y;
}

// ---------------------------------------------------------------------------
// Kernel 3: fused expert FFN v5.
// 48.5KB LDS -> 3 blocks/CU. Per chunk (64 f): GEMM1 (64x64, K=256, X from
// L2 gather + W1 from LDS via async global_load_lds) -> relu -> Hs (XOR-
// swizzled, dbuf) -> GEMM2 (64x256 partial, K=64, w2 from L2 contiguous).
// W1 staging of chunk ch overlaps GEMM2 of chunk ch-1.
// ---------------------------------------------------------------------------
__global__ __launch_bounds__(256, 3) void moe_kernel(
    const bf16_t* __restrict__ xb,
    const bf16_t* __restrict__ w1t,
    const float*  __restrict__ b1,
    const bf16_t* __restrict__ w2t,
    const float*  __restrict__ b2,
    const int* __restrict__ counts,
    const int* __restrict__ bucket_enc,
    const float* __restrict__ bucket_gw,
    bf16_t* __restrict__ pairbuf)    // [NTOK*2][NH] bf16
{
    __shared__ __align__(16) bf16_t W1s[64 * 256];   // 32 KB, one chunk image
    __shared__ __align__(16) bf16_t Hs[2][64 * 64];  // 16 KB
    __shared__ int   tok_s[TT];
    __shared__ float gw_s[TT];

    int flat = blockIdx.x;                  // 768 blocks
    int e     = (flat & 7) * 2 + ((flat >> 3) & 1);   // 2 experts per XCD
    int tile0 = flat >> 4;                  // 0..47
    int n_e = counts[e];
    int wave = threadIdx.x >> 6;
    int lane = threadIdx.x & 63;
    int l15 = lane & 15, q = lane >> 4;
    int mbase = (wave & 1) * 32;            // GEMM1 m-range
    int nbase = (wave >> 1) * 32;           // GEMM1 n-range (f within chunk)

    const bf16_t* w1te = w1t + (size_t)e * EW;
    const bf16_t* w2te = w2t + (size_t)e * EW;

    int ntiles = (n_e + TT - 1) / TT;
    for (int tile = tile0; tile < ntiles; tile += 48) {
        int tstart = tile * TT;
        __syncthreads();   // protect LDS reuse across tile iterations
        if (threadIdx.x < TT) {
            int slot = tstart + threadIdx.x;
            if (slot < n_e) {
                tok_s[threadIdx.x] = bucket_enc[e * NTOK + slot];
                gw_s [threadIdx.x] = bucket_gw [e * NTOK + slot];
            } else { tok_s[threadIdx.x] = 0; gw_s[threadIdx.x] = 0.f; }
        }
        __syncthreads();

        // per-lane X row pointers for the wave's two m-frags
        const bf16_t* xr0 = xb + (size_t)(tok_s[mbase + l15] & 0xFFFFF) * NH + q * 8;
        const bf16_t* xr1 = xb + (size_t)(tok_s[mbase + 16 + l15] & 0xFFFFF) * NH + q * 8;
        // GEMM1 B-row bases + xor masks for the wave's two n-frags
        int fl0 = nbase + l15, fl1 = nbase + 16 + l15;

        f32x4 oacc[4][4];
        #pragma unroll
        for (int a = 0; a < 4; a++)
            #pragma unroll
            for (int b = 0; b < 4; b++) { f32x4 z = {0.f,0.f,0.f,0.f}; oacc[a][b] = z; }

        #define STAGE_W1(CH) do {                                            \
            const bf16_t* gch = w1te + (CH) * 16384;                         \
            _Pragma("unroll")                                                \
            for (int i = 0; i < 8; i++) {                                    \
                int seg = wave * 8 + i;                                      \
                __builtin_amdgcn_global_load_lds(                            \
                    (const __attribute__((address_space(1))) void*)          \
                        (gch + seg * 512 + lane * 8),                        \
                    (__attribute__((address_space(3))) void*)(&W1s[seg * 512]), \
                    16, 0, 0);                                               \
            }                                                                \
        } while (0)

        #define GEMM1(CH) do {                                               \
            f32x4 hacc[2][2];                                                \
            _Pragma("unroll")                                                \
            for (int a = 0; a < 2; a++)                                      \
                _Pragma("unroll")                                            \
                for (int b = 0; b < 2; b++) { f32x4 z = {0.f,0.f,0.f,0.f}; hacc[a][b] = z; } \
            _Pragma("unroll 4")                                              \
            for (int ks = 0; ks < 8; ks++) {                                 \
                bf16x8 af0 = *(const bf16x8*)(xr0 + ks * 32);                \
                bf16x8 af1 = *(const bf16x8*)(xr1 + ks * 32);                \
                int g = ks * 4 + q;                                          \
                bf16x8 bf0 = *(const bf16x8*)&W1s[fl0 * 256 + (((g & 24) | ((g ^ fl0) & 7)) << 3)]; \
                bf16x8 bf1 = *(const bf16x8*)&W1s[fl1 * 256 + (((g & 24) | ((g ^ fl1) & 7)) << 3)]; \
                hacc[0][0] = __builtin_amdgcn_mfma_f32_16x16x32_bf16(af0, bf0, hacc[0][0], 0, 0, 0); \
                hacc[1][0] = __builtin_amdgcn_mfma_f32_16x16x32_bf16(af1, bf0, hacc[1][0], 0, 0, 0); \
                hacc[0][1] = __builtin_amdgcn_mfma_f32_16x16x32_bf16(af0, bf1, hacc[0][1], 0, 0, 0); \
                hacc[1][1] = __builtin_amdgcn_mfma_f32_16x16x32_bf16(af1, bf1, hacc[1][1], 0, 0, 0); \
            }                                                                \
            int buf = (CH) & 1;                                              \
            float b1v0 = b1[e * NF + (CH) * 64 + fl0];                       \
            float b1v1 = b1[e * NF + (CH) * 64 + fl1];                       \
            _Pragma("unroll")                                                \
            for (int ni = 0; ni < 2; ni++) {                                 \
                int col = nbase + ni * 16 + l15;                             \
                int cg = col >> 3;                                           \
                float bv = ni ? b1v1 : b1v0;                                 \
                _Pragma("unroll")                                            \
                for (int mi = 0; mi < 2; mi++) {                             \
                    _Pragma("unroll")                                        \
                    for (int r = 0; r < 4; r++) {                            \
                        int row = mbase + mi * 16 + q * 4 + r;               \
                        float v = hacc[mi][ni][r] + bv;                      \
                        v = v > 0.f ? v : 0.f;                               \
                        Hs[buf][row * 64 + ((cg ^ (row & 7)) << 3) + (col & 7)] = (bf16_t)v; \
                    }                                                        \
                }                                                            \
            }                                                                \
        } while (0)

        #define GEMM2(CH) do {                                               \
            int buf = (CH) & 1;                                              \
            _Pragma("unroll")                                                \
            for (int ks2 = 0; ks2 < 2; ks2++) {                              \
                bf16x8 af2[4], bf2[4];                                       \
                _Pragma("unroll")                                            \
                for (int mt = 0; mt < 4; mt++) {                             \
                    int row = mt * 16 + l15;                                 \
                    int cg = ks2 * 4 + q;                                    \
                    af2[mt] = *(const bf16x8*)&Hs[buf][row * 64 + ((cg ^ (row & 7)) << 3)]; \
                }                                                            \
                _Pragma("unroll")                                            \
                for (int nt = 0; nt < 4; nt++) {                             \
                    int hh = wave * 64 + nt * 16 + l15;                      \
                    bf2[nt] = *(const bf16x8*)&w2te[((size_t)((CH) * 8 + ks2 * 4 + q)) * 2048 + hh * 8]; \
                }                                                            \
                _Pragma("unroll")                                            \
                for (int mt = 0; mt < 4; mt++)                               \
                    _Pragma("unroll")                                        \
                    for (int nt = 0; nt < 4; nt++)                           \
                        oacc[mt][nt] = __builtin_amdgcn_mfma_f32_16x16x32_bf16(af2[mt], bf2[nt], oacc[mt][nt], 0, 0, 0); \
            }                                                                \
        } while (0)

        STAGE_W1(0);
        __syncthreads();          // drains vmcnt: W1s chunk 0 ready
        GEMM1(0);
        __syncthreads();          // Hs[0] visible; W1s readers done
        #pragma unroll 1
        for (int ch = 1; ch < 8; ch++) {
            STAGE_W1(ch);         // async into W1s (safe: readers drained)
            GEMM2(ch - 1);        // overlaps the staging latency
            __syncthreads();      // drains vmcnt; all GEMM2 reads done
            GEMM1(ch);
            __syncthreads();
        }
        GEMM2(7);

        // ---- epilogue: +b2, *gate_weight, scatter to pair buffer
        #pragma unroll
        for (int nt = 0; nt < 4; nt++) {
            int col = wave * 64 + nt * 16 + l15;
            float b2v = b2[e * NH + col];
            #pragma unroll
            for (int mt = 0; mt < 4; mt++) {
                #pragma unroll
                for (int r = 0; r < 4; r++) {
                    int row = mt * 16 + q * 4 + r;
                    if (tstart + row < n_e) {
                        int enc = tok_s[row];
                        int tok = enc & 0xFFFFF;
                        int k   = enc >> 20;
                        float v = (oacc[mt][nt][r] + b2v) * gw_s[row];
                        pairbuf[((size_t)(tok * 2 + k)) * NH + col] = (bf16_t)v;
                    }
                }
            }
        }
        #undef STAGE_W1
        #undef GEMM1
        #undef GEMM2
    }
}

// ---------------------------------------------------------------------------
// Kernel 4: residual + LayerNorm, wave-per-token, float4, shuffle-only
// ---------------------------------------------------------------------------
__global__ __launch_bounds__(256) void ln_kernel(
    const float* __restrict__ x, const bf16_t* __restrict__ pairbuf,
    const float* __restrict__ gamma, const float* __restrict__ beta,
    float* __restrict__ out)
{
    int wave = threadIdx.x >> 6, lane = threadIdx.x & 63;
    int tok = blockIdx.x * 4 + wave;
    float4 xv = ((const float4*)(x + (size_t)tok * NH))[lane];
    bf16x4 p0 = ((const bf16x4*)(pairbuf + (size_t)(tok * 2) * NH))[lane];
    bf16x4 p1 = ((const bf16x4*)(pairbuf + (size_t)(tok * 2 + 1) * NH))[lane];
    float4 y;
    y.x = xv.x + (float)p0[0] + (float)p1[0];
    y.y = xv.y + (float)p0[1] + (float)p1[1];
    y.z = xv.z + (float)p0[2] + (float)p1[2];
    y.w = xv.w + (float)p0[3] + (float)p1[3];
    float s  = y.x + y.y + y.z + y.w;
    float s2 = y.x*y.x + y.y*y.y + y.z*y.z + y.w*y.w;
    #pragma unroll
    for (int o = 32; o > 0; o >>= 1) {
        s  += __shfl_xor(s, o);
        s2 += __shfl_xor(s2, o);
    }
    float mu  = s * (1.f / NH);
    float var = s2 * (1.f / NH) - mu * mu;
    float rstd = rsqrtf(var + 1e-5f);
    float4 g4 = ((const float4*)gamma)[lane];
    float4 b4 = ((const float4*)beta)[lane];
    float4 o4;
    o4.x = (y.x - mu) * rstd * g4.x + b4.x;
    o4.y = (y.y - mu) * rstd * g4.y + b4.y;
    o4.z = (y.z - mu) * rstd * g4.z + b4.z;
    o4.w = (y.w - mu) * rstd * g4.w + b4.w;
    ((float4*)(out + (size_t)tok * NH))[lane] = o4;
}

// ---------------------------------------------------------------------------
extern "C" void kernel_launch(void* const* d_in, const int* in_sizes, int n_in,
                              void* d_out, int out_size, void* d_ws, size_t ws_size,
                              hipStream_t stream) {
    const float* x      = (const float*)d_in[0];
    const float* gate_w = (const float*)d_in[1];
    const float* gate_b = (const float*)d_in[2];
    const float* w1     = (const float*)d_in[3];
    const float* b1     = (const float*)d_in[4];
    const float* w2     = (const float*)d_in[5];
    const float* b2     = (const float*)d_in[6];
    const float* gamma  = (const float*)d_in[7];
    const float* beta   = (const float*)d_in[8];
    float* out = (float*)d_out;

    char* ws = (char*)d_ws;
    const size_t KB = 1024, MB = 1024 * 1024;
    int*    counts     = (int*)ws;                       // 64 B
    int*    blockcnt   = (int*)(ws + 4  * KB);           // 8 KB
    int*    segb       = (int*)(ws + 12 * KB);           // 8 KB
    int*    pick_e     = (int*)(ws + 64 * KB);           // 128 KB
    int*    pick_r     = (int*)(ws + 192 * KB);          // 128 KB
    float2* pick_w     = (float2*)(ws + 320 * KB);       // 256 KB
    int*    bucket_enc = (int*)(ws + 1 * MB);            // 2 MB
    float*  bucket_gw  = (float*)(ws + 3 * MB);          // 2 MB
    bf16_t* w1t        = (bf16_t*)(ws + 5 * MB);         // 4 MB
    bf16_t* w2t        = (bf16_t*)(ws + 9 * MB);         // 4 MB
    bf16_t* xb         = (bf16_t*)(ws + 13 * MB);        // 16 MB
    bf16_t* pairbuf    = (bf16_t*)(ws + 29 * MB);        // 32 MB

    transpose_kernel<<<4096, 256, 0, stream>>>(w1, w2, w1t, w2t);
    gate_kernel<<<128, 256, 0, stream>>>(x, gate_w, gate_b, blockcnt,
                                         pick_e, pick_r, pick_w, xb);
    scan_kernel<<<1, 256, 0, stream>>>(blockcnt, segb, counts);
    scatter_kernel<<<128, 256, 0, stream>>>(pick_e, pick_r, pick_w, segb,
                                            bucket_enc, bucket_gw);
    moe_kernel<<<768, 256, 0, stream>>>(xb, w1t, b1, w2t, b2, counts,
                                        bucket_enc, bucket_gw, pairbuf);
    ln_kernel<<<NTOK / 4, 256, 0, stream>>>(x, pairbuf, gamma, beta, out);
}